// Round 1
// baseline (49339.365 us; speedup 1.0000x reference)
//
#include <hip/hip_runtime.h>
#include <math.h>

#define Tn 256
#define Bn 64
#define Hn 512
#define CHUNK 64
#define EPSF 1e-15f

__device__ __forceinline__ float artanh_f(float x){
  x = fminf(fmaxf(x, -1.0f + 1e-7f), 1.0f - 1e-7f);
  return 0.5f * (log1pf(x) - log1pf(-x));
}

// 256-thread block reduce of 3 floats; result broadcast to all threads.
__device__ __forceinline__ void block_reduce3(float& a, float& b, float& c, float* red){
  #pragma unroll
  for (int off = 32; off > 0; off >>= 1){
    a += __shfl_xor(a, off);
    b += __shfl_xor(b, off);
    c += __shfl_xor(c, off);
  }
  const int tid = threadIdx.x;
  const int w = tid >> 6;
  __syncthreads();                       // protect red from previous use
  if ((tid & 63) == 0){ red[w] = a; red[4+w] = b; red[8+w] = c; }
  __syncthreads();
  a = red[0]+red[1]+red[2]+red[3];
  b = red[4]+red[5]+red[6]+red[7];
  c = red[8]+red[9]+red[10]+red[11];
}

// ---------------- precompute GEMM: C[r][c] = dot(A[r,:512], B[c,:512]) -------
#define GBM 64
#define GBN 64
#define GBK 16

__global__ __launch_bounds__(256) void gemm_tn(
    const float* __restrict__ A,   // M x 512 row-major (M = CHUNK*Bn)
    const float* __restrict__ Bm,  // 1536 x 512 row-major
    float* __restrict__ Cm)        // M x 1536
{
  __shared__ __align__(16) float As[GBK][GBM];
  __shared__ __align__(16) float Bs[GBK][GBN];
  const int tid = threadIdx.x;
  const int rm0 = blockIdx.x * GBM;
  const int cn0 = blockIdx.y * GBN;
  const int lr = tid >> 2;          // 0..63
  const int lk = (tid & 3) * 4;     // 0,4,8,12
  const int tx = tid & 15;
  const int ty = tid >> 4;
  float acc[4][4] = {};
  const float* Arow = A  + (size_t)(rm0 + lr) * 512 + lk;
  const float* Brow = Bm + (size_t)(cn0 + lr) * 512 + lk;
  for (int k0 = 0; k0 < 512; k0 += GBK){
    const float4 av = *reinterpret_cast<const float4*>(Arow + k0);
    const float4 bv = *reinterpret_cast<const float4*>(Brow + k0);
    __syncthreads();
    As[lk+0][lr]=av.x; As[lk+1][lr]=av.y; As[lk+2][lr]=av.z; As[lk+3][lr]=av.w;
    Bs[lk+0][lr]=bv.x; Bs[lk+1][lr]=bv.y; Bs[lk+2][lr]=bv.z; Bs[lk+3][lr]=bv.w;
    __syncthreads();
    #pragma unroll
    for (int kk = 0; kk < GBK; ++kk){
      const float4 a4 = *reinterpret_cast<const float4*>(&As[kk][tx*4]);
      const float4 b4 = *reinterpret_cast<const float4*>(&Bs[kk][ty*4]);
      const float ar[4] = {a4.x, a4.y, a4.z, a4.w};
      const float br[4] = {b4.x, b4.y, b4.z, b4.w};
      #pragma unroll
      for (int i = 0; i < 4; ++i)
        #pragma unroll
        for (int j = 0; j < 4; ++j)
          acc[i][j] = fmaf(ar[i], br[j], acc[i][j]);
    }
  }
  #pragma unroll
  for (int i = 0; i < 4; ++i){
    float4 st; st.x=acc[i][0]; st.y=acc[i][1]; st.z=acc[i][2]; st.w=acc[i][3];
    *reinterpret_cast<float4*>(&Cm[(size_t)(rm0 + tx*4 + i)*1536 + cn0 + ty*4]) = st;
  }
}

// ------- apply mobius_matvec scaling to P rows: P = tanh(mn/xn*artanh(xn))*P/mn
__global__ __launch_bounds__(256) void scale_kernel(
    const float* __restrict__ src,  // nrows x 512 (the layer input rows)
    float* __restrict__ P)          // nrows x 1536 (mx, scaled in place)
{
  __shared__ float red[12];
  const int row = blockIdx.x, tid = threadIdx.x;
  const float x0 = src[(size_t)row*512 + tid];
  const float x1 = src[(size_t)row*512 + tid + 256];
  float xn2 = x0*x0 + x1*x1, d1 = 0.f, d2 = 0.f;
  block_reduce3(xn2, d1, d2, red);
  const float xn = sqrtf(xn2 + EPSF);
  const float artx = artanh_f(xn);
  float* Prow = P + (size_t)row*1536;
  #pragma unroll
  for (int g = 0; g < 3; ++g){
    const float p0 = Prow[g*512 + tid];
    const float p1 = Prow[g*512 + tid + 256];
    float mn2 = p0*p0 + p1*p1, e1 = 0.f, e2 = 0.f;
    block_reduce3(mn2, e1, e2, red);
    const float mn = sqrtf(mn2 + EPSF);
    const float s = tanhf(mn / xn * artx) / mn;
    Prow[g*512 + tid]       = s * p0;
    Prow[g*512 + tid + 256] = s * p1;
  }
}

// ---------------- one GRU cell step: block = batch row b ----------------
__global__ __launch_bounds__(256) void cell_kernel(
    const float* __restrict__ Whh,   // (1536,512) this layer: [r | hid | z]
    const float* __restrict__ bias,  // (3,512): [b_r, b_h, b_z]
    const float* __restrict__ P,     // chunk rows x 1536 (scaled x-side)
    float* __restrict__ h,           // (B,H) in/out
    float* __restrict__ outseq,      // (T,B,H)
    float* __restrict__ lastdst,     // (B,H) or nullptr
    int t, int tc)
{
  __shared__ __align__(16) float hs[Hn];
  __shared__ __align__(16) float rhs[Hn];
  __shared__ float red[12];
  const int b = blockIdx.x;
  const int tid = threadIdx.x;
  const int j0 = tid, j1 = tid + 256;

  float h0 = h[(size_t)b*Hn + j0];
  float h1 = h[(size_t)b*Hn + j1];
  hs[j0] = h0; hs[j1] = h1;
  float hn2 = h0*h0 + h1*h1, u1 = 0.f, u2 = 0.f;
  block_reduce3(hn2, u1, u2, red);   // barriers also publish hs
  const float xn_h = sqrtf(hn2 + EPSF);
  const float artx_h = artanh_f(xn_h);

  const float* Prow = P + (size_t)(tc*Bn + b) * 1536;

  auto matvec = [&](const float* W, const float* vs, float& m0, float& m1){
    const float4* w0 = reinterpret_cast<const float4*>(W + (size_t)j0 * Hn);
    const float4* w1 = reinterpret_cast<const float4*>(W + (size_t)j1 * Hn);
    const float4* v4 = reinterpret_cast<const float4*>(vs);
    float a0 = 0.f, a1 = 0.f;
    #pragma unroll 8
    for (int k = 0; k < Hn/4; ++k){
      const float4 wa = w0[k], wb = w1[k], x = v4[k];
      a0 = fmaf(wa.x, x.x, a0); a0 = fmaf(wa.y, x.y, a0);
      a0 = fmaf(wa.z, x.z, a0); a0 = fmaf(wa.w, x.w, a0);
      a1 = fmaf(wb.x, x.x, a1); a1 = fmaf(wb.y, x.y, a1);
      a1 = fmaf(wb.z, x.z, a1); a1 = fmaf(wb.w, x.w, a1);
    }
    m0 = a0; m1 = a1;
  };

  // mobius_matvec(Whh[go:], vs) ⊕ P[seg] ⊕ bias[bi]  (⊕ = mobius_add),
  // optionally followed by sigmoid(logmap0(.)) for gates.
  auto chain = [&](int go, int seg, int bi, float xn_o, float artx_o,
                   const float* vs, bool gate, float& o0, float& o1){
    float m0, m1;
    matvec(Whh + (size_t)go * Hn, vs, m0, m1);
    float mn2 = m0*m0 + m1*m1, r1 = 0.f, r2 = 0.f;
    block_reduce3(mn2, r1, r2, red);
    const float mn = sqrtf(mn2 + EPSF);
    const float s = tanhf(mn / xn_o * artx_o) / mn;
    const float v0 = s*m0, v1 = s*m1;
    const float x2 = s*s*mn2;
    // mobius_add(v, p)
    const float p0 = Prow[seg*Hn + j0], p1 = Prow[seg*Hn + j1];
    float y2 = p0*p0 + p1*p1, xy = v0*p0 + v1*p1, r3 = 0.f;
    block_reduce3(y2, xy, r3, red);
    float na = 1.f + 2.f*xy + y2;
    float nb = 1.f - x2;
    float den = fmaxf(1.f + 2.f*xy + x2*y2, EPSF);
    const float q0 = (na*v0 + nb*p0) / den;
    const float q1 = (na*v1 + nb*p1) / den;
    // mobius_add(q, bias)
    const float bb0 = bias[bi*Hn + j0], bb1 = bias[bi*Hn + j1];
    float qx2 = q0*q0 + q1*q1;
    float by2 = bb0*bb0 + bb1*bb1;
    float bxy = q0*bb0 + q1*bb1;
    block_reduce3(qx2, by2, bxy, red);
    na = 1.f + 2.f*bxy + by2;
    nb = 1.f - qx2;
    den = fmaxf(1.f + 2.f*bxy + qx2*by2, EPSF);
    const float w0v = (na*q0 + nb*bb0) / den;
    const float w1v = (na*q1 + nb*bb1) / den;
    if (gate){
      float wn2 = w0v*w0v + w1v*w1v, s1 = 0.f, s2 = 0.f;
      block_reduce3(wn2, s1, s2, red);
      const float yn = sqrtf(wn2 + EPSF);
      const float sc = artanh_f(yn) / yn;
      o0 = 1.f / (1.f + expf(-sc * w0v));
      o1 = 1.f / (1.f + expf(-sc * w1v));
    } else { o0 = w0v; o1 = w1v; }
  };

  // r gate (Whh rows [0:512), P seg 0, bias 0)
  float r0, r1g;
  chain(0, 0, 0, xn_h, artx_h, hs, true, r0, r1g);

  // rh = mobius_pw_mul(r, h)
  const float w0 = r0*h0, w1 = r1g*h1;
  float wn2 = w0*w0 + w1*w1, d1 = 0.f, d2 = 0.f;
  block_reduce3(wn2, d1, d2, red);
  const float wn = sqrtf(wn2 + EPSF);
  const float s_rh = tanhf(wn / xn_h * artx_h) / wn;
  rhs[j0] = s_rh*w0; rhs[j1] = s_rh*w1;
  const float rhn2 = s_rh*s_rh*wn2;
  const float xn_rh = sqrtf(rhn2 + EPSF);
  const float artx_rh = artanh_f(xn_rh);

  // z gate (Whh rows [1024:1536), P seg 2, bias 2); its internal barriers
  // also publish rhs for the h~ chain below.
  float z0, z1g;
  chain(1024, 2, 2, xn_h, artx_h, hs, true, z0, z1g);

  // h_tilde (Whh rows [512:1024), operand rh, P seg 1, bias 1)
  float ht0, ht1;
  chain(512, 1, 1, xn_rh, artx_rh, rhs, false, ht0, ht1);

  // delta = mobius_add(-h, h_tilde)
  float htn2 = ht0*ht0 + ht1*ht1;
  float hht  = h0*ht0 + h1*ht1;
  float r5 = 0.f;
  block_reduce3(htn2, hht, r5, red);
  {
    const float y2 = htn2, xy = -hht;
    const float na = 1.f + 2.f*xy + y2;
    const float nb = 1.f - hn2;
    const float den = fmaxf(1.f + 2.f*xy + hn2*y2, EPSF);
    ht0 = (na*(-h0) + nb*ht0) / den;   // ht now holds delta
    ht1 = (na*(-h1) + nb*ht1) / den;
  }

  // pw = mobius_pw_mul(z, delta); h_new = mobius_add(h, pw)
  const float wz0 = z0*ht0, wz1 = z1g*ht1;
  float dn2  = ht0*ht0 + ht1*ht1;
  float wzn2 = wz0*wz0 + wz1*wz1;
  float hwz  = h0*wz0 + h1*wz1;
  block_reduce3(dn2, wzn2, hwz, red);
  const float dn  = sqrtf(dn2 + EPSF);
  const float wzn = sqrtf(wzn2 + EPSF);
  const float s_pw = tanhf(wzn / dn * artanh_f(dn)) / wzn;
  const float y2p = s_pw*s_pw*wzn2;
  const float xyp = s_pw*hwz;
  const float na = 1.f + 2.f*xyp + y2p;
  const float nb = 1.f - hn2;
  const float den = fmaxf(1.f + 2.f*xyp + hn2*y2p, EPSF);
  const float hn0 = (na*h0 + nb*s_pw*wz0) / den;
  const float hn1 = (na*h1 + nb*s_pw*wz1) / den;

  h[(size_t)b*Hn + j0] = hn0;
  h[(size_t)b*Hn + j1] = hn1;
  outseq[((size_t)t*Bn + b)*Hn + j0] = hn0;
  outseq[((size_t)t*Bn + b)*Hn + j1] = hn1;
  if (lastdst){
    lastdst[(size_t)b*Hn + j0] = hn0;
    lastdst[(size_t)b*Hn + j1] = hn1;
  }
}

extern "C" void kernel_launch(void* const* d_in, const int* in_sizes, int n_in,
                              void* d_out, int out_size, void* d_ws, size_t ws_size,
                              hipStream_t stream)
{
  const float* inp  = (const float*)d_in[0];   // (T,B,H)
  const float* Wih  = (const float*)d_in[1];   // (L,3H,H)
  const float* Whh  = (const float*)d_in[2];   // (L,3H,H)
  const float* bias = (const float*)d_in[3];   // (L,3,H)
  float* out  = (float*)d_out;                 // (T,B,H)
  float* last = out + (size_t)Tn*Bn*Hn;        // (L,B,H)

  float* P    = (float*)d_ws;                        // CHUNK*Bn x 1536
  float* hbuf = P + (size_t)CHUNK*Bn*1536;           // Bn x Hn

  for (int l = 0; l < 2; ++l){
    const float* src   = (l == 0) ? inp : out;  // layer-1 consumes layer-0 seq
    const float* Wihl  = Wih  + (size_t)l*1536*Hn;
    const float* Whhl  = Whh  + (size_t)l*1536*Hn;
    const float* biasl = bias + (size_t)l*3*Hn;
    hipMemsetAsync(hbuf, 0, (size_t)Bn*Hn*sizeof(float), stream);
    for (int c = 0; c < Tn/CHUNK; ++c){
      const float* srcc = src + (size_t)c*CHUNK*Bn*Hn;
      dim3 gg(CHUNK*Bn/GBM, 1536/GBN);
      hipLaunchKernelGGL(gemm_tn, gg, dim3(256), 0, stream, srcc, Wihl, P);
      hipLaunchKernelGGL(scale_kernel, dim3(CHUNK*Bn), dim3(256), 0, stream,
                         srcc, P);
      for (int tt = 0; tt < CHUNK; ++tt){
        const int t = c*CHUNK + tt;
        float* ld = (t == Tn-1) ? (last + (size_t)l*Bn*Hn) : nullptr;
        hipLaunchKernelGGL(cell_kernel, dim3(Bn), dim3(256), 0, stream,
                           Whhl, biasl, P, hbuf, out, ld, t, tt);
      }
    }
  }
}

// Round 2
// 13909.288 us; speedup vs baseline: 3.5472x; 3.5472x over previous
//
#include <hip/hip_runtime.h>
#include <math.h>

#define Tn 256
#define Bn 64
#define Hn 512
#define CHUNK 32
#define EPSF 1e-15f

__device__ __forceinline__ float artanh_f(float x){
  x = fminf(fmaxf(x, -1.0f + 1e-7f), 1.0f - 1e-7f);
  return 0.5f * (log1pf(x) - log1pf(-x));
}

// 256-thread block reduce of N floats; results broadcast to all threads.
template<int N>
__device__ __forceinline__ void block_reduceN(float* v, float* red){
  #pragma unroll
  for (int off = 32; off > 0; off >>= 1){
    #pragma unroll
    for (int n = 0; n < N; ++n) v[n] += __shfl_xor(v[n], off);
  }
  const int tid = threadIdx.x;
  const int w = tid >> 6;
  __syncthreads();
  if ((tid & 63) == 0){
    #pragma unroll
    for (int n = 0; n < N; ++n) red[n*4 + w] = v[n];
  }
  __syncthreads();
  #pragma unroll
  for (int n = 0; n < N; ++n)
    v[n] = red[n*4+0] + red[n*4+1] + red[n*4+2] + red[n*4+3];
}

// ---------------- precompute GEMM: C[r][c] = dot(A[r,:512], B[c,:512]) -------
#define GBM 64
#define GBN 64
#define GBK 16

__global__ __launch_bounds__(256) void gemm_tn(
    const float* __restrict__ A,   // M x 512 row-major (M = CHUNK*Bn)
    const float* __restrict__ Bm,  // 1536 x 512 row-major
    float* __restrict__ Cm)        // M x 1536
{
  __shared__ __align__(16) float As[GBK][GBM];
  __shared__ __align__(16) float Bs[GBK][GBN];
  const int tid = threadIdx.x;
  const int rm0 = blockIdx.x * GBM;
  const int cn0 = blockIdx.y * GBN;
  const int lr = tid >> 2;
  const int lk = (tid & 3) * 4;
  const int tx = tid & 15;
  const int ty = tid >> 4;
  float acc[4][4] = {};
  const float* Arow = A  + (size_t)(rm0 + lr) * 512 + lk;
  const float* Brow = Bm + (size_t)(cn0 + lr) * 512 + lk;
  for (int k0 = 0; k0 < 512; k0 += GBK){
    const float4 av = *reinterpret_cast<const float4*>(Arow + k0);
    const float4 bv = *reinterpret_cast<const float4*>(Brow + k0);
    __syncthreads();
    As[lk+0][lr]=av.x; As[lk+1][lr]=av.y; As[lk+2][lr]=av.z; As[lk+3][lr]=av.w;
    Bs[lk+0][lr]=bv.x; Bs[lk+1][lr]=bv.y; Bs[lk+2][lr]=bv.z; Bs[lk+3][lr]=bv.w;
    __syncthreads();
    #pragma unroll
    for (int kk = 0; kk < GBK; ++kk){
      const float4 a4 = *reinterpret_cast<const float4*>(&As[kk][tx*4]);
      const float4 b4 = *reinterpret_cast<const float4*>(&Bs[kk][ty*4]);
      const float ar[4] = {a4.x, a4.y, a4.z, a4.w};
      const float br[4] = {b4.x, b4.y, b4.z, b4.w};
      #pragma unroll
      for (int i = 0; i < 4; ++i)
        #pragma unroll
        for (int j = 0; j < 4; ++j)
          acc[i][j] = fmaf(ar[i], br[j], acc[i][j]);
    }
  }
  #pragma unroll
  for (int i = 0; i < 4; ++i){
    float4 st; st.x=acc[i][0]; st.y=acc[i][1]; st.z=acc[i][2]; st.w=acc[i][3];
    *reinterpret_cast<float4*>(&Cm[(size_t)(rm0 + tx*4 + i)*1536 + cn0 + ty*4]) = st;
  }
}

// ------- apply mobius_matvec scaling to P rows -------------------------------
__global__ __launch_bounds__(256) void scale_kernel(
    const float* __restrict__ src,  // nrows x 512 (layer input rows)
    float* __restrict__ P)          // nrows x 1536 (mx, scaled in place)
{
  __shared__ float red[24];
  const int row = blockIdx.x, tid = threadIdx.x;
  const float x0 = src[(size_t)row*512 + tid];
  const float x1 = src[(size_t)row*512 + tid + 256];
  float v[3];
  v[0] = x0*x0 + x1*x1; v[1] = 0.f; v[2] = 0.f;
  block_reduceN<3>(v, red);
  const float xn = sqrtf(v[0] + EPSF);
  const float artx = artanh_f(xn);
  float* Prow = P + (size_t)row*1536;
  // three segment norms in one reduce
  float p[6];
  #pragma unroll
  for (int g = 0; g < 3; ++g){
    p[2*g]   = Prow[g*512 + tid];
    p[2*g+1] = Prow[g*512 + tid + 256];
  }
  float m[3];
  #pragma unroll
  for (int g = 0; g < 3; ++g) m[g] = p[2*g]*p[2*g] + p[2*g+1]*p[2*g+1];
  block_reduceN<3>(m, red);
  #pragma unroll
  for (int g = 0; g < 3; ++g){
    const float mn = sqrtf(m[g] + EPSF);
    const float s = tanhf(mn / xn * artx) / mn;
    Prow[g*512 + tid]       = s * p[2*g];
    Prow[g*512 + tid + 256] = s * p[2*g+1];
  }
}

// ---------------- row-distributed matvec: M[b][gr] = dot(W[row], X[b]) -------
#define RT 16
#define BT 16

__global__ __launch_bounds__(256) void matvec_tiled(
    const float* __restrict__ Whh,  // (1536,512) layer weights
    const float* __restrict__ X,    // (64,512) operand (h or rh)
    float* __restrict__ M,          // out, row-major (64, out_stride)
    int mode, int out_stride)       // mode0: rows {0:512,1024:1536}; mode1: rows 512+gr
{
  __shared__ __align__(16) float hs[BT][516];
  const int tid = threadIdx.x;
  const int bg = blockIdx.y * BT;
  for (int idx = tid*4; idx < BT*512; idx += 1024){
    const int r = idx >> 9, c = idx & 511;
    const float4 vv = *reinterpret_cast<const float4*>(&X[(size_t)(bg + r)*512 + c]);
    *reinterpret_cast<float4*>(&hs[r][c]) = vv;
  }
  __syncthreads();
  const int i = tid >> 4, jb = tid & 15;
  const int gr = blockIdx.x * RT + i;
  const int row = (mode == 0) ? (gr < 512 ? gr : gr + 512) : (gr + 512);
  const float4* wp = reinterpret_cast<const float4*>(Whh + (size_t)row * 512);
  const float* hrow = hs[jb];
  float a0 = 0.f, a1 = 0.f, a2 = 0.f, a3 = 0.f;
  #pragma unroll 8
  for (int k = 0; k < 128; ++k){
    const float4 w = wp[k];
    const float4 x = *reinterpret_cast<const float4*>(&hrow[k*4]);
    a0 = fmaf(w.x, x.x, a0);
    a1 = fmaf(w.y, x.y, a1);
    a2 = fmaf(w.z, x.z, a2);
    a3 = fmaf(w.w, x.w, a3);
  }
  M[(size_t)(bg + jb) * out_stride + gr] = (a0 + a1) + (a2 + a3);
}

// ---------------- gates r,z + rh (one block per batch row) -------------------
__global__ __launch_bounds__(256) void gate_mid_kernel(
    const float* __restrict__ Mrz,   // (B,1024): [Mr | Mz]
    const float* __restrict__ bias,  // (3,512)
    const float* __restrict__ P,     // chunk rows x 1536
    const float* __restrict__ h,     // (B,512)
    float* __restrict__ rhout,       // (B,512)
    float* __restrict__ zout,        // (B,512)
    int tc)
{
  __shared__ float red[24];
  const int b = blockIdx.x, tid = threadIdx.x;
  const int j0 = tid, j1 = tid + 256;
  const float h0 = h[(size_t)b*512 + j0], h1 = h[(size_t)b*512 + j1];
  const float mr0 = Mrz[(size_t)b*1024 + j0],       mr1 = Mrz[(size_t)b*1024 + j1];
  const float mz0 = Mrz[(size_t)b*1024 + 512 + j0], mz1 = Mrz[(size_t)b*1024 + 512 + j1];
  float v[6];
  v[0] = h0*h0 + h1*h1;
  v[1] = mr0*mr0 + mr1*mr1;
  v[2] = mz0*mz0 + mz1*mz1;
  block_reduceN<3>(v, red);
  const float hn2 = v[0];
  const float xn_h = sqrtf(hn2 + EPSF);
  const float artx_h = artanh_f(xn_h);
  const float mn2r = v[1], mn2z = v[2];
  const float mnr = sqrtf(mn2r + EPSF), mnz = sqrtf(mn2z + EPSF);
  const float sr = tanhf(mnr / xn_h * artx_h) / mnr;
  const float sz = tanhf(mnz / xn_h * artx_h) / mnz;
  const float vr0 = sr*mr0, vr1 = sr*mr1;
  const float vz0 = sz*mz0, vz1 = sz*mz1;
  const float x2r = sr*sr*mn2r, x2z = sz*sz*mn2z;
  const float* Prow = P + (size_t)(tc*Bn + b)*1536;
  const float pr0 = Prow[j0], pr1 = Prow[j1];
  const float pz0 = Prow[1024 + j0], pz1 = Prow[1024 + j1];
  v[0] = pr0*pr0 + pr1*pr1;  v[1] = vr0*pr0 + vr1*pr1;
  v[2] = pz0*pz0 + pz1*pz1;  v[3] = vz0*pz0 + vz1*pz1;
  block_reduceN<4>(v, red);
  float na = 1.f + 2.f*v[1] + v[0];
  float nb = 1.f - x2r;
  float den = fmaxf(1.f + 2.f*v[1] + x2r*v[0], EPSF);
  const float qr0 = (na*vr0 + nb*pr0)/den, qr1 = (na*vr1 + nb*pr1)/den;
  na = 1.f + 2.f*v[3] + v[2];
  nb = 1.f - x2z;
  den = fmaxf(1.f + 2.f*v[3] + x2z*v[2], EPSF);
  const float qz0 = (na*vz0 + nb*pz0)/den, qz1 = (na*vz1 + nb*pz1)/den;
  const float br0 = bias[j0], br1 = bias[j1];
  const float bz0 = bias[1024 + j0], bz1 = bias[1024 + j1];
  v[0] = qr0*qr0 + qr1*qr1;  v[1] = br0*br0 + br1*br1;  v[2] = qr0*br0 + qr1*br1;
  v[3] = qz0*qz0 + qz1*qz1;  v[4] = bz0*bz0 + bz1*bz1;  v[5] = qz0*bz0 + qz1*bz1;
  block_reduceN<6>(v, red);
  na = 1.f + 2.f*v[2] + v[1];
  nb = 1.f - v[0];
  den = fmaxf(1.f + 2.f*v[2] + v[0]*v[1], EPSF);
  const float wr0 = (na*qr0 + nb*br0)/den, wr1 = (na*qr1 + nb*br1)/den;
  na = 1.f + 2.f*v[5] + v[4];
  nb = 1.f - v[3];
  den = fmaxf(1.f + 2.f*v[5] + v[3]*v[4], EPSF);
  const float wz0 = (na*qz0 + nb*bz0)/den, wz1 = (na*qz1 + nb*bz1)/den;
  v[0] = wr0*wr0 + wr1*wr1;
  v[1] = wz0*wz0 + wz1*wz1;
  block_reduceN<2>(v, red);
  const float ynr = sqrtf(v[0] + EPSF);
  const float scr = artanh_f(ynr) / ynr;
  const float r0 = 1.f/(1.f + expf(-scr*wr0)), r1 = 1.f/(1.f + expf(-scr*wr1));
  const float ynz = sqrtf(v[1] + EPSF);
  const float scz = artanh_f(ynz) / ynz;
  const float z0 = 1.f/(1.f + expf(-scz*wz0)), z1 = 1.f/(1.f + expf(-scz*wz1));
  // rh = mobius_pw_mul(r, h)
  const float w0 = r0*h0, w1 = r1*h1;
  v[0] = w0*w0 + w1*w1;
  block_reduceN<1>(v, red);
  const float wn = sqrtf(v[0] + EPSF);
  const float s_rh = tanhf(wn / xn_h * artx_h) / wn;
  rhout[(size_t)b*512 + j0] = s_rh*w0;
  rhout[(size_t)b*512 + j1] = s_rh*w1;
  zout[(size_t)b*512 + j0] = z0;
  zout[(size_t)b*512 + j1] = z1;
}

// ---------------- finish: h~ chain, delta, h_new -----------------------------
__global__ __launch_bounds__(256) void finish_kernel(
    const float* __restrict__ Mh,    // (B,512)
    const float* __restrict__ bias,  // (3,512)
    const float* __restrict__ P,     // chunk rows x 1536
    const float* __restrict__ rhv,   // (B,512)
    const float* __restrict__ zv,    // (B,512)
    float* __restrict__ h,           // (B,512) in/out
    float* __restrict__ outseq,      // (T,B,H)
    float* __restrict__ lastdst,     // (B,H) or nullptr
    int t, int tc)
{
  __shared__ float red[24];
  const int b = blockIdx.x, tid = threadIdx.x;
  const int j0 = tid, j1 = tid + 256;
  const float h0 = h[(size_t)b*512 + j0],  h1 = h[(size_t)b*512 + j1];
  const float rh0 = rhv[(size_t)b*512 + j0], rh1 = rhv[(size_t)b*512 + j1];
  const float m0 = Mh[(size_t)b*512 + j0],  m1 = Mh[(size_t)b*512 + j1];
  float v[3];
  v[0] = h0*h0 + h1*h1;
  v[1] = rh0*rh0 + rh1*rh1;
  v[2] = m0*m0 + m1*m1;
  block_reduceN<3>(v, red);
  const float hn2 = v[0];
  const float xn_rh = sqrtf(v[1] + EPSF);
  const float artx = artanh_f(xn_rh);
  const float mn2 = v[2];
  const float mn = sqrtf(mn2 + EPSF);
  const float s = tanhf(mn / xn_rh * artx) / mn;
  const float v0 = s*m0, v1s = s*m1;
  const float x2 = s*s*mn2;
  const float* Prow = P + (size_t)(tc*Bn + b)*1536 + 512;   // seg 1 (hid)
  const float p0 = Prow[j0], p1 = Prow[j1];
  v[0] = p0*p0 + p1*p1;  v[1] = v0*p0 + v1s*p1;
  block_reduceN<2>(v, red);
  float na = 1.f + 2.f*v[1] + v[0];
  float nb = 1.f - x2;
  float den = fmaxf(1.f + 2.f*v[1] + x2*v[0], EPSF);
  const float q0 = (na*v0 + nb*p0)/den, q1 = (na*v1s + nb*p1)/den;
  const float bb0 = bias[512 + j0], bb1 = bias[512 + j1];
  v[0] = q0*q0 + q1*q1;  v[1] = bb0*bb0 + bb1*bb1;  v[2] = q0*bb0 + q1*bb1;
  block_reduceN<3>(v, red);
  na = 1.f + 2.f*v[2] + v[1];
  nb = 1.f - v[0];
  den = fmaxf(1.f + 2.f*v[2] + v[0]*v[1], EPSF);
  float ht0 = (na*q0 + nb*bb0)/den, ht1 = (na*q1 + nb*bb1)/den;
  // delta = mobius_add(-h, ht)
  v[0] = ht0*ht0 + ht1*ht1;  v[1] = h0*ht0 + h1*ht1;
  block_reduceN<2>(v, red);
  {
    const float y2 = v[0], xy = -v[1];
    na = 1.f + 2.f*xy + y2;
    nb = 1.f - hn2;
    den = fmaxf(1.f + 2.f*xy + hn2*y2, EPSF);
    const float d0 = (na*(-h0) + nb*ht0)/den;
    const float d1 = (na*(-h1) + nb*ht1)/den;
    ht0 = d0; ht1 = d1;
  }
  const float z0 = zv[(size_t)b*512 + j0], z1 = zv[(size_t)b*512 + j1];
  const float wz0 = z0*ht0, wz1 = z1*ht1;
  v[0] = ht0*ht0 + ht1*ht1;
  v[1] = wz0*wz0 + wz1*wz1;
  v[2] = h0*wz0 + h1*wz1;
  block_reduceN<3>(v, red);
  const float dn  = sqrtf(v[0] + EPSF);
  const float wzn = sqrtf(v[1] + EPSF);
  const float s_pw = tanhf(wzn / dn * artanh_f(dn)) / wzn;
  const float y2p = s_pw*s_pw*v[1];
  const float xyp = s_pw*v[2];
  na = 1.f + 2.f*xyp + y2p;
  nb = 1.f - hn2;
  den = fmaxf(1.f + 2.f*xyp + hn2*y2p, EPSF);
  const float hn0 = (na*h0 + nb*s_pw*wz0)/den;
  const float hn1 = (na*h1 + nb*s_pw*wz1)/den;
  h[(size_t)b*512 + j0] = hn0;
  h[(size_t)b*512 + j1] = hn1;
  outseq[((size_t)t*Bn + b)*512 + j0] = hn0;
  outseq[((size_t)t*Bn + b)*512 + j1] = hn1;
  if (lastdst){
    lastdst[(size_t)b*512 + j0] = hn0;
    lastdst[(size_t)b*512 + j1] = hn1;
  }
}

extern "C" void kernel_launch(void* const* d_in, const int* in_sizes, int n_in,
                              void* d_out, int out_size, void* d_ws, size_t ws_size,
                              hipStream_t stream)
{
  const float* inp  = (const float*)d_in[0];   // (T,B,H)
  const float* Wih  = (const float*)d_in[1];   // (L,3H,H)
  const float* Whh  = (const float*)d_in[2];   // (L,3H,H)
  const float* bias = (const float*)d_in[3];   // (L,3,H)
  float* out  = (float*)d_out;                 // (T,B,H)
  float* last = out + (size_t)Tn*Bn*Hn;        // (L,B,H)

  float* P    = (float*)d_ws;                       // CHUNK*Bn x 1536
  float* hbuf = P + (size_t)CHUNK*Bn*1536;          // Bn x Hn
  float* Mrz  = hbuf + (size_t)Bn*Hn;               // Bn x 1024
  float* Mh   = Mrz + (size_t)Bn*1024;              // Bn x 512
  float* rhb  = Mh + (size_t)Bn*512;                // Bn x 512
  float* zb   = rhb + (size_t)Bn*512;               // Bn x 512

  for (int l = 0; l < 2; ++l){
    const float* src   = (l == 0) ? inp : out;
    const float* Wihl  = Wih  + (size_t)l*1536*Hn;
    const float* Whhl  = Whh  + (size_t)l*1536*Hn;
    const float* biasl = bias + (size_t)l*3*Hn;
    hipMemsetAsync(hbuf, 0, (size_t)Bn*Hn*sizeof(float), stream);
    for (int c = 0; c < Tn/CHUNK; ++c){
      const float* srcc = src + (size_t)c*CHUNK*Bn*Hn;
      dim3 gg(CHUNK*Bn/GBM, 1536/GBN);
      hipLaunchKernelGGL(gemm_tn, gg, dim3(256), 0, stream, srcc, Wihl, P);
      hipLaunchKernelGGL(scale_kernel, dim3(CHUNK*Bn), dim3(256), 0, stream,
                         srcc, P);
      for (int tt = 0; tt < CHUNK; ++tt){
        const int t = c*CHUNK + tt;
        float* ld = (t == Tn-1) ? (last + (size_t)l*Bn*Hn) : nullptr;
        hipLaunchKernelGGL(matvec_tiled, dim3(1024/RT, Bn/BT), dim3(256), 0,
                           stream, Whhl, hbuf, Mrz, 0, 1024);
        hipLaunchKernelGGL(gate_mid_kernel, dim3(Bn), dim3(256), 0, stream,
                           Mrz, biasl, P, hbuf, rhb, zb, tt);
        hipLaunchKernelGGL(matvec_tiled, dim3(512/RT, Bn/BT), dim3(256), 0,
                           stream, Whhl, rhb, Mh, 1, 512);
        hipLaunchKernelGGL(finish_kernel, dim3(Bn), dim3(256), 0, stream,
                           Mh, biasl, P, rhb, zb, hbuf, out, ld, t, tt);
      }
    }
  }
}